// Round 9
// baseline (116.514 us; speedup 1.0000x reference)
//
#include <hip/hip_runtime.h>
#include <hip/hip_bf16.h>

#define NN_ 8192
#define DD_ 128
#define NCLS 512
#define NB 64      /* bands */
#define BR 128     /* rows per band */

typedef short bf16x8 __attribute__((ext_vector_type(8)));
typedef float f32x4 __attribute__((ext_vector_type(4)));

union U4 { uint4 u; bf16x8 h; };

#if __has_builtin(__builtin_amdgcn_exp2f)
#define EXP2(x) __builtin_amdgcn_exp2f(x)
#else
#define EXP2(x) __expf((x) * 0.69314718056f)
#endif

#define C1 115.415603f  /* 80*log2(e); 0.16*C1 + C2 == C1 exactly */
#define LN2 0.69314718056f
#define NEGM -1e30f

__device__ __forceinline__ unsigned short f2bf(float f) {
    unsigned int u = __float_as_uint(f);
    unsigned int r = (u + 0x7FFFu + ((u >> 16) & 1u)) >> 16;  // RNE
    return (unsigned short)r;
}

// Fragment-swizzled layout (uint4 units): fb[grp*256 + chunk*16 + row16].
// Rows label-sorted. R9: SYMMETRY — block = unordered band pair {I, J=(I+d)&63},
// d=0..31 x I=0..63 (2048 blocks) + d=32 x I=0..31 (32) = 2080 blocks.
// e/tp are functions of s only -> computed once per pair, credited to row-side
// (rows in I, slot rowstates[d]) AND col-side (rows in J, per-wave partial in
// colstates[d-1][wave]). Diagonal d=0: row-side only (covers both orders).
// Slots per row: 33 rowplanes + 128 colplanes; planes rowstates[32] (bands>=32)
// and colstates[31][*] (bands<32) are neutral-inited in k_scatnorm.
// Sorted classes are contiguous -> one wave-uniform window test [lo,hi) detects
// positives for BOTH sides of a subtile.

// ---------------- kernel 0: hist + scan (1 block) -------------------------------
__global__ __launch_bounds__(1024) void k_sorthead(const int* __restrict__ labels,
                                                   int* __restrict__ start,
                                                   int* __restrict__ base) {
    __shared__ int hist[NCLS];
    __shared__ int wsum[8];
    int t = threadIdx.x;
    if (t < NCLS) hist[t] = 0;
    __syncthreads();
    int4 la = ((const int4*)labels)[t * 2];
    int4 lb = ((const int4*)labels)[t * 2 + 1];
    atomicAdd(&hist[la.x], 1); atomicAdd(&hist[la.y], 1);
    atomicAdd(&hist[la.z], 1); atomicAdd(&hist[la.w], 1);
    atomicAdd(&hist[lb.x], 1); atomicAdd(&hist[lb.y], 1);
    atomicAdd(&hist[lb.z], 1); atomicAdd(&hist[lb.w], 1);
    __syncthreads();
    int v = (t < NCLS) ? hist[t] : 0;
    int x = v;
#pragma unroll
    for (int m = 1; m < 64; m <<= 1) {
        int y = __shfl_up(x, m);
        if ((t & 63) >= m) x += y;
    }
    if (t < NCLS && (t & 63) == 63) wsum[t >> 6] = x;
    __syncthreads();
    if (t < NCLS) {
        int w = t >> 6, woff = 0;
#pragma unroll
        for (int k = 0; k < 8; k++)
            if (k < w) woff += wsum[k];
        int excl = woff + x - v;
        start[t] = excl;
        base[t] = excl;
        if (t == 0) start[NCLS] = NN_;
    }
}

// ---------------- kernel 1: fused scatter + neutral-init + normalize -----------
__global__ __launch_bounds__(256) void k_scatnorm(const float* __restrict__ x,
                                                  const int* __restrict__ labels,
                                                  int* __restrict__ base,
                                                  int* __restrict__ plab,
                                                  unsigned short* __restrict__ ebf,
                                                  float4* __restrict__ rowstates,
                                                  float4* __restrict__ colstates) {
    __shared__ int sp[16];
    int t = threadIdx.x;
    if (t < 16) {
        int row = blockIdx.x * 16 + t;
        int l = labels[row];
        int p = atomicAdd(&base[l], 1);
        plab[p] = l;
        sp[t] = p;
        float4 neu = {NEGM, 0.f, 0.f, 0.f};
        if (p >= NN_ / 2) {
            rowstates[32 * NN_ + p] = neu;           // rowplane 32 unwritten for bands>=32
        } else {
#pragma unroll
            for (int w = 0; w < 4; w++)
                colstates[(31 * 4 + w) * NN_ + p] = neu;  // colplane d=32 unwritten for bands<32
        }
    }
    __syncthreads();
    int r16 = t >> 4;
    int g = t & 15;
    int row = blockIdx.x * 16 + r16;
    const float4* xr = (const float4*)(x + (size_t)row * DD_);
    float4 v0 = xr[g * 2];
    float4 v1 = xr[g * 2 + 1];
    float ss = v0.x * v0.x + v0.y * v0.y + v0.z * v0.z + v0.w * v0.w +
               v1.x * v1.x + v1.y * v1.y + v1.z * v1.z + v1.w * v1.w;
#pragma unroll
    for (int m = 1; m < 16; m <<= 1) ss += __shfl_xor(ss, m);
    float inv = 1.0f / fmaxf(sqrtf(ss), 1e-12f);
    float vs[8] = {v0.x, v0.y, v0.z, v0.w, v1.x, v1.y, v1.z, v1.w};
    unsigned int p[4];
#pragma unroll
    for (int k = 0; k < 4; k++) {
        unsigned short lo = f2bf(vs[2 * k] * inv);
        unsigned short hi = f2bf(vs[2 * k + 1] * inv);
        p[k] = (unsigned int)lo | ((unsigned int)hi << 16);
    }
    uint4 out = {p[0], p[1], p[2], p[3]};
    int dst = sp[r16];
    ((uint4*)ebf)[(dst >> 4) * 256 + g * 16 + (dst & 15)] = out;
}

// ---------------- kernel 2: symmetric sim + both-sided LSE ----------------------
// 2080 blocks x 256 threads (4 waves x 32 rows = 128-row I-band); J-band 128
// cols as 4 x 32-col LDS tiles (2x8KB dbuf, async-split staging).
__global__ __launch_bounds__(256, 4) void k_main(const unsigned short* __restrict__ ebf,
                                                 const int* __restrict__ plab,
                                                 const int* __restrict__ start,
                                                 float4* __restrict__ rowstates,
                                                 float4* __restrict__ colstates) {
    __shared__ uint4 bsh[1024];  // 2 buffers x 512 uint4 (8KB each)

    const int tid = threadIdx.x;
    const int lane = tid & 63;
    const int wave = tid >> 6;   // 0..3
    const int quad = lane >> 4;
    const int lcol = lane & 15;
    int bid = blockIdx.x;
    int d, I;
    if (bid < 2048) { d = bid >> 6; I = bid & 63; }
    else            { d = 32;       I = bid - 2048; }
    const int J = (I + d) & 63;
    const int rowbase = I * BR + wave * 32;
    const int j0 = J * BR;

    const uint4* fb = (const uint4*)ebf;

    U4 afr[2][4];
#pragma unroll
    for (int g = 0; g < 2; g++)
#pragma unroll
        for (int kc = 0; kc < 4; kc++)
            afr[g][kc].u = fb[((rowbase >> 4) + g) * 256 + kc * 64 + lane];

    int il[2][4];
#pragma unroll
    for (int g = 0; g < 2; g++)
#pragma unroll
        for (int r = 0; r < 4; r++) il[g][r] = plab[rowbase + g * 16 + quad * 4 + r];

    int labmin = __builtin_amdgcn_readfirstlane(plab[rowbase]);
    int labmax = __builtin_amdgcn_readfirstlane(plab[rowbase + 31]);
    int lo = __builtin_amdgcn_readfirstlane(start[labmin]);
    int hi = __builtin_amdgcn_readfirstlane(start[labmax + 1]);

    float S_an[2][4], m_p[2][4], s_p[2][4];
#pragma unroll
    for (int g = 0; g < 2; g++)
#pragma unroll
        for (int r = 0; r < 4; r++) { S_an[g][r] = 0.f; m_p[g][r] = NEGM; s_p[g][r] = 0.f; }

    const f32x4 Z = {0.f, 0.f, 0.f, 0.f};

    // prologue: stage cols j0..j0+31 (8KB) into buffer 0
    {
        const int tb = (j0 >> 4) * 256;
        bsh[tid] = fb[tb + tid];
        bsh[tid + 256] = fb[tb + tid + 256];
    }
    __syncthreads();

#pragma unroll
    for (int it = 0; it < 4; ++it) {
        const int cur = it & 1;
        const int jt = j0 + it * 32;
        const bool has = (it < 3);

        uint4 stg0, stg1;
        if (has) {
            const int tn = ((jt + 32) >> 4) * 256;
            stg0 = fb[tn + tid];
            stg1 = fb[tn + tid + 256];
        }

        const int bbase = (cur << 9) + lane;

#pragma unroll
        for (int c = 0; c < 2; c++) {
            U4 bf[4];
#pragma unroll
            for (int kc = 0; kc < 4; kc++) bf[kc].u = bsh[bbase + c * 256 + kc * 64];
            f32x4 acc0 = __builtin_amdgcn_mfma_f32_16x16x32_bf16(afr[0][0].h, bf[0].h, Z, 0, 0, 0);
            f32x4 acc1 = __builtin_amdgcn_mfma_f32_16x16x32_bf16(afr[1][0].h, bf[0].h, Z, 0, 0, 0);
#pragma unroll
            for (int kc = 1; kc < 4; kc++) {
                acc0 = __builtin_amdgcn_mfma_f32_16x16x32_bf16(afr[0][kc].h, bf[kc].h, acc0, 0, 0, 0);
                acc1 = __builtin_amdgcn_mfma_f32_16x16x32_bf16(afr[1][kc].h, bf[kc].h, acc1, 0, 0, 0);
            }
            const int jc = jt + c * 16;
            float cm = NEGM, cs = 0.f, cS = 0.f;  // col-side subtile state (this lane's column)
            if (jc < hi && jc + 16 > lo) {
                int jl = plab[jc + lcol];
                int j = jc + lcol;
#pragma unroll
                for (int g = 0; g < 2; g++) {
#pragma unroll
                    for (int r = 0; r < 4; r++) {
                        float s = (g == 0) ? acc0[r] : acc1[r];
                        int i = rowbase + g * 16 + quad * 4 + r;
                        bool same = (jl == il[g][r]);
                        float u = fmaxf(s, -0.4f);
                        float e = EXP2(fmaf(u * C1, u, -C1));
                        float ee = same ? 0.0f : e;
                        S_an[g][r] += ee;
                        cS += ee;
                        if (same) {
                            float tp = fmaxf(1.4f - s, 0.0f) * (-C1) * (s - 0.6f);
                            if (j != i) {
                                float mn = fmaxf(m_p[g][r], tp);
                                s_p[g][r] = s_p[g][r] * EXP2(m_p[g][r] - mn) + EXP2(tp - mn);
                                m_p[g][r] = mn;
                            }
                            float mn2 = fmaxf(cm, tp);  // col-side positive (i!=j when d>0)
                            cs = cs * EXP2(cm - mn2) + EXP2(tp - mn2);
                            cm = mn2;
                        }
                    }
                }
            } else {
                // pure negative fast path: e once, credited to both sides
#pragma unroll
                for (int r = 0; r < 4; r++) {
                    float u0 = fmaxf(acc0[r], -0.4f);
                    float e0 = EXP2(fmaf(u0 * C1, u0, -C1));
                    S_an[0][r] += e0;
                    float u1 = fmaxf(acc1[r], -0.4f);
                    float e1 = EXP2(fmaf(u1 * C1, u1, -C1));
                    S_an[1][r] += e1;
                    cS += e0 + e1;
                }
            }
            if (d) {
                // merge col state across the 4 quad groups (same column, diff rows)
#pragma unroll
                for (int mm = 16; mm < 64; mm <<= 1) {
                    float m2 = __shfl_xor(cm, mm);
                    float s2 = __shfl_xor(cs, mm);
                    float S2 = __shfl_xor(cS, mm);
                    float mn = fmaxf(cm, m2);
                    cs = cs * EXP2(cm - mn) + s2 * EXP2(m2 - mn);
                    cm = mn;
                    cS += S2;
                }
                if (lane < 16) {
                    float4 st = {cm, cs, cS, 0.f};
                    colstates[((d - 1) * 4 + wave) * NN_ + jc + lcol] = st;
                }
            }
        }

        if (has) {
            bsh[((cur ^ 1) << 9) + tid] = stg0;
            bsh[((cur ^ 1) << 9) + tid + 256] = stg1;
        }
        __syncthreads();
    }

    // row-side merge across the 16 column-stripes, store rowstates[d][i]
#pragma unroll
    for (int g = 0; g < 2; g++)
#pragma unroll
        for (int r = 0; r < 4; r++) {
#pragma unroll
            for (int m = 1; m < 16; m <<= 1) {
                S_an[g][r] += __shfl_xor(S_an[g][r], m);
                float m2 = __shfl_xor(m_p[g][r], m);
                float s2 = __shfl_xor(s_p[g][r], m);
                float mn = fmaxf(m_p[g][r], m2);
                s_p[g][r] = s_p[g][r] * EXP2(m_p[g][r] - mn) + s2 * EXP2(m2 - mn);
                m_p[g][r] = mn;
            }
        }
    if (lcol == 0) {
#pragma unroll
        for (int g = 0; g < 2; g++)
#pragma unroll
            for (int r = 0; r < 4; r++) {
                int i = rowbase + g * 16 + quad * 4 + r;
                float4 st = {m_p[g][r], s_p[g][r], S_an[g][r], 0.f};
                rowstates[d * NN_ + i] = st;
            }
    }
}

// ---------------- kernel 3: merge 33 row-planes + 128 col-planes per row --------
__global__ __launch_bounds__(64) void k_fin(const float4* __restrict__ rowstates,
                                            const float4* __restrict__ colstates,
                                            const int* __restrict__ plab,
                                            const int* __restrict__ start,
                                            float* __restrict__ partials) {
    int i = blockIdx.x * 64 + threadIdx.x;
    float m_p = NEGM, s_p = 0.f, S_an = 0.f;
    for (int p = 0; p < 33; p++) {
        float4 st = rowstates[p * NN_ + i];
        S_an += st.z;
        float mn = fmaxf(m_p, st.x);
        s_p = s_p * EXP2(m_p - mn) + st.y * EXP2(st.x - mn);
        m_p = mn;
    }
    for (int p = 0; p < 128; p++) {
        float4 st = colstates[p * NN_ + i];
        S_an += st.z;
        float mn = fmaxf(m_p, st.x);
        s_p = s_p * EXP2(m_p - mn) + st.y * EXP2(st.x - mn);
        m_p = mn;
    }
    int l = plab[i];
    int sz = start[l + 1] - start[l];
    int np = sz - 1;
    int nn = NN_ - sz;
    float loss = 0.0f, v = 0.0f;
    if (np > 0 && nn > 0 && s_p > 0.f && S_an > 0.f) {
        float lse_p = LN2 * m_p + __logf(s_p);
        float lse_n = 67.2f + __logf(S_an);
        float z = lse_p + lse_n + __logf((float)np) + __logf((float)nn);
        loss = fmaxf(z, 0.0f) + log1pf(__expf(-fabsf(z)));  // stable softplus
        v = 1.0f;
    }
#pragma unroll
    for (int m = 1; m < 64; m <<= 1) {
        loss += __shfl_xor(loss, m);
        v += __shfl_xor(v, m);
    }
    if (threadIdx.x == 0) {
        partials[blockIdx.x * 2] = loss;
        partials[blockIdx.x * 2 + 1] = v;
    }
}

// ---------------- kernel 4: final reduce over 128 wave-partials -----------------
__global__ void k_div(const float* __restrict__ partials, float* __restrict__ out) {
    int t = threadIdx.x;  // 64 threads
    float loss = partials[t * 2] + partials[(t + 64) * 2];
    float v = partials[t * 2 + 1] + partials[(t + 64) * 2 + 1];
#pragma unroll
    for (int m = 1; m < 64; m <<= 1) {
        loss += __shfl_xor(loss, m);
        v += __shfl_xor(v, m);
    }
    if (t == 0) out[0] = loss / fmaxf(v, 1.0f);
}

// ---------------- launch --------------------------------------------------------
extern "C" void kernel_launch(void* const* d_in, const int* in_sizes, int n_in,
                              void* d_out, int out_size, void* d_ws, size_t ws_size,
                              hipStream_t stream) {
    const float* embeds = (const float*)d_in[0];
    const int* labels = (const int*)d_in[1];
    float* out = (float*)d_out;

    char* ws = (char*)d_ws;
    unsigned short* ebf = (unsigned short*)ws;          // 2,097,152 B
    float4* rowstates = (float4*)(ws + 2097152);        // 33*8192*16 = 4,325,376 B
    float4* colstates = (float4*)(ws + 6422528);        // 128*8192*16 = 16,777,216 B
    float* partials = (float*)(ws + 23199744);          // 1,024 B
    int* plab = (int*)(ws + 23200768);                  // 32,768 B
    int* start = (int*)(ws + 23233536);                 // 2,052 B (513 ints)
    int* base = (int*)(ws + 23235840);                  // 2,048 B

    k_sorthead<<<1, 1024, 0, stream>>>(labels, start, base);
    k_scatnorm<<<NN_ / 16, 256, 0, stream>>>(embeds, labels, base, plab, ebf, rowstates, colstates);
    k_main<<<2080, 256, 0, stream>>>(ebf, plab, start, rowstates, colstates);
    k_fin<<<NN_ / 64, 64, 0, stream>>>(rowstates, colstates, plab, start, partials);
    k_div<<<1, 64, 0, stream>>>(partials, out);
}